// Round 5
// baseline (275.209 us; speedup 1.0000x reference)
//
#include <hip/hip_runtime.h>
#include <hip/hip_bf16.h>

// Self-attention: q=X@Wq.T+bq, k=..., v=...; S = causal_softmax(q k^T / 32); O = S v
// B=4, S=2048, D_IN=D_OUT=1024. fp32 in/out; internal compute bf16 MFMA + fp32 acc.
//
// R5 change: gemm_qkv_fused retiled 128x128 -> 128x64 (grid 16x64).
//   acc[3][4][2] = 96 AGPR (was 192) -> ~2 blocks/CU resident (was ~1), so two
//   blocks' K-loops interleave across each other's barrier drains (m114
//   wave-level co-scheduling). 24 MFMA/wave/barrier, 5 stage16/iter (was 8),
//   LDS 20 KB. scores/pv deliberately unchanged this round (diagnostic: with
//   qkv faster, their true durations surface in the top-5 profile).
//
// MFMA fragment layouts (HW-verified per guide §3):
//  A: lane holds A[m=lane&15][k=(lane>>4)*8+j], j=0..7
//  B: lane holds B[k=(lane>>4)*8+j][n=lane&15]
//  C/D: lane holds D[row=(lane>>4)*4+e][col=lane&15], e=0..3

typedef __attribute__((ext_vector_type(8))) short short8;   // 8 bf16 = 4 VGPRs
typedef __attribute__((ext_vector_type(4))) float floatx4;  // MFMA acc

#define SEQ   2048
#define DMODEL 1024
#define NBATCH 4
#define MTOT  (SEQ * NBATCH)   // 8192 rows for the projection GEMM

// Direct global->LDS async copy, 16B per lane. LDS dst is wave-uniform base +
// lane*16 (per-lane scatter NOT supported) — our tile layout is lane-contiguous.
__device__ __forceinline__ void stage16(const __hip_bfloat16* g, __hip_bfloat16* l)
{
  __builtin_amdgcn_global_load_lds(
      (const __attribute__((address_space(1))) void*)g,
      (__attribute__((address_space(3))) void*)l, 16, 0, 0);
}

__device__ __forceinline__ unsigned short bf16_bits(float f)
{
  __hip_bfloat16 h = __float2bfloat16(f);
  return *(unsigned short*)&h;
}

// ---------------------------------------------------------------------------
// One-kernel fp32 -> bf16 convert for all four inputs. Each block: 1024 elems.
__global__ __launch_bounds__(256) void convert_all(
    const float* __restrict__ X,  const float* __restrict__ Wq,
    const float* __restrict__ Wk, const float* __restrict__ Wv,
    __hip_bfloat16* __restrict__ Xb,  __hip_bfloat16* __restrict__ Wqb,
    __hip_bfloat16* __restrict__ Wkb, __hip_bfloat16* __restrict__ Wvb)
{
  const int b = blockIdx.x;
  const float* src; __hip_bfloat16* dst; int rel;
  if (b < 8192)       { src = X;  dst = Xb;  rel = b; }
  else if (b < 9216)  { src = Wq; dst = Wqb; rel = b - 8192; }
  else if (b < 10240) { src = Wk; dst = Wkb; rel = b - 9216; }
  else                { src = Wv; dst = Wvb; rel = b - 10240; }
  const int i = rel * 1024 + threadIdx.x * 4;
  float4 f = *(const float4*)(src + i);
  uint2 o;
  o.x = (unsigned)bf16_bits(f.x) | ((unsigned)bf16_bits(f.y) << 16);
  o.y = (unsigned)bf16_bits(f.z) | ((unsigned)bf16_bits(f.w) << 16);
  *(uint2*)(dst + i) = o;
}

// ---------------------------------------------------------------------------
// Fused QKV projection, 128m x 64n tile. A-tile (X) staged once per k-iter,
// three 64x32 B-tiles. Waves 2x2: wm in {0,64}, wn in {0,32}; each wave owns
// 64x32 per weight -> acc[3][4][2]. Q,K row-major; V transposed to Vt.
// grid = (DMODEL/64=16, MTOT/128=64), 256 threads, 20 KB LDS.
__global__ __launch_bounds__(256, 2) void gemm_qkv_fused(
    const __hip_bfloat16* __restrict__ Xb,
    const __hip_bfloat16* __restrict__ Wqb,
    const __hip_bfloat16* __restrict__ Wkb,
    const __hip_bfloat16* __restrict__ Wvb,
    const float* __restrict__ bq, const float* __restrict__ bk, const float* __restrict__ bv,
    __hip_bfloat16* __restrict__ Qb, __hip_bfloat16* __restrict__ Kb, __hip_bfloat16* __restrict__ Vt)
{
  __shared__ __hip_bfloat16 As[128 * 32];
  __shared__ __hip_bfloat16 Bs[3][64 * 32];
  const int m0 = blockIdx.y * 128, n0 = blockIdx.x * 64;
  const int tid  = threadIdx.x;
  const int lane = tid & 63;
  const int wave = tid >> 6;
  const int quad = lane >> 4;
  const int r    = lane & 15;
  const int wm   = (wave >> 1) * 64;
  const int wn   = (wave & 1) * 32;
  const int srow = wave * 16 + (lane >> 2);   // 0..63
  const int scol = (lane & 3) * 8;            // 0,8,16,24

  const __hip_bfloat16* Wp[3] = {Wqb, Wkb, Wvb};

  __hip_bfloat16* lA0 = As + wave * 512;
  __hip_bfloat16* lA1 = As + 2048 + wave * 512;

  const __hip_bfloat16* aR0 = Xb + (size_t)(m0 + srow) * DMODEL + scol;
  const __hip_bfloat16* aR1 = aR0 + (size_t)64 * DMODEL;

  floatx4 acc[3][4][2] = {};

  for (int kt = 0; kt < DMODEL / 32; ++kt) {
    const int k0 = kt * 32;
    stage16(aR0 + k0, lA0);
    stage16(aR1 + k0, lA1);
#pragma unroll
    for (int w = 0; w < 3; ++w)
      stage16(Wp[w] + (size_t)(n0 + srow) * DMODEL + scol + k0, Bs[w] + wave * 512);
    __syncthreads();
    short8 a[4];
#pragma unroll
    for (int i = 0; i < 4; ++i)
      a[i] = *(const short8*)(As + (wm + i * 16 + r) * 32 + quad * 8);
#pragma unroll
    for (int w = 0; w < 3; ++w) {
      short8 b[2];
#pragma unroll
      for (int j = 0; j < 2; ++j)
        b[j] = *(const short8*)(Bs[w] + (wn + j * 16 + r) * 32 + quad * 8);
#pragma unroll
      for (int i = 0; i < 4; ++i)
#pragma unroll
        for (int j = 0; j < 2; ++j)
          acc[w][i][j] = __builtin_amdgcn_mfma_f32_16x16x32_bf16(a[i], b[j], acc[w][i][j], 0, 0, 0);
    }
    __syncthreads();
  }

  // Q, K: row-major stores
  {
    __hip_bfloat16* Op[2] = {Qb, Kb};
    const float* Bp[2] = {bq, bk};
#pragma unroll
    for (int w = 0; w < 2; ++w) {
      __hip_bfloat16* out = Op[w];
#pragma unroll
      for (int j = 0; j < 2; ++j) {
        const int n = n0 + wn + j * 16 + r;
        const float bb = Bp[w][n];
#pragma unroll
        for (int i = 0; i < 4; ++i) {
          const int mbase = m0 + wm + i * 16 + quad * 4;
#pragma unroll
          for (int e = 0; e < 4; ++e)
            out[(size_t)(mbase + e) * DMODEL + n] = __float2bfloat16(acc[w][i][j][e] + bb);
        }
      }
    }
  }
  // V: transposed store Vt[z][d=n][pos], 8B packed per (i,j). z = batch of m0.
  {
    const int z    = m0 >> 11;           // SEQ = 2048
    const int posb = (m0 & (SEQ - 1)) + wm;
    __hip_bfloat16* vt = Vt + (size_t)z * DMODEL * SEQ;
#pragma unroll
    for (int j = 0; j < 2; ++j) {
      const int n = n0 + wn + j * 16 + r;
      const float bb = bv[n];
#pragma unroll
      for (int i = 0; i < 4; ++i) {
        const int pos = posb + i * 16 + quad * 4;
        unsigned long long pk =
            (unsigned long long)bf16_bits(acc[2][i][j][0] + bb)
          | ((unsigned long long)bf16_bits(acc[2][i][j][1] + bb) << 16)
          | ((unsigned long long)bf16_bits(acc[2][i][j][2] + bb) << 32)
          | ((unsigned long long)bf16_bits(acc[2][i][j][3] + bb) << 48);
        *(unsigned long long*)(vt + (size_t)n * SEQ + pos) = pk;
      }
    }
  }
}

// ---------------------------------------------------------------------------
// Shared GEMM core for scores/pv: C[128x128] += A * B^T, bf16 row-major [.,K].
__device__ __forceinline__ void gemm_core(
    const __hip_bfloat16* __restrict__ A,
    const __hip_bfloat16* __restrict__ B,
    int K, int m0, int n0, int ktiles,
    __hip_bfloat16* As, __hip_bfloat16* Bs,
    floatx4 acc[4][4])
{
  const int tid  = threadIdx.x;
  const int lane = tid & 63;
  const int wave = tid >> 6;
  const int quad = lane >> 4;
  const int r    = lane & 15;
  const int wm   = (wave >> 1) * 64;
  const int wn   = (wave & 1) * 64;
  const int srow = wave * 16 + (lane >> 2);
  const int scol = (lane & 3) * 8;
  __hip_bfloat16* lA0 = As + wave * 512;
  __hip_bfloat16* lA1 = As + 2048 + wave * 512;
  __hip_bfloat16* lB0 = Bs + wave * 512;
  __hip_bfloat16* lB1 = Bs + 2048 + wave * 512;

  for (int kt = 0; kt < ktiles; ++kt) {
    const int k0 = kt * 32;
    stage16(A + (size_t)(m0 + srow) * K + k0 + scol,      lA0);
    stage16(A + (size_t)(m0 + 64 + srow) * K + k0 + scol, lA1);
    stage16(B + (size_t)(n0 + srow) * K + k0 + scol,      lB0);
    stage16(B + (size_t)(n0 + 64 + srow) * K + k0 + scol, lB1);
    __syncthreads();
    short8 a[4], b[4];
#pragma unroll
    for (int i = 0; i < 4; ++i)
      a[i] = *(const short8*)(As + (wm + i * 16 + r) * 32 + quad * 8);
#pragma unroll
    for (int j = 0; j < 4; ++j)
      b[j] = *(const short8*)(Bs + (wn + j * 16 + r) * 32 + quad * 8);
#pragma unroll
    for (int i = 0; i < 4; ++i)
#pragma unroll
      for (int j = 0; j < 4; ++j)
        acc[i][j] = __builtin_amdgcn_mfma_f32_16x16x32_bf16(a[i], b[j], acc[i][j], 0, 0, 0);
    __syncthreads();
  }
}

// ---------------------------------------------------------------------------
// Scores: P'[z][q][k] = exp((Qb_z Kb_z^T)[q][k]/32) for k<=q (0 above diagonal
// within the diagonal tile), stored bf16. Per-row partial sums atomically
// accumulated into lsum[z*SEQ+q] (fp32, zeroed beforehand). Tiles fully above
// the diagonal: no compute, no write (PV never reads them).
__global__ __launch_bounds__(256) void gemm_scores(
    const __hip_bfloat16* __restrict__ Qb, const __hip_bfloat16* __restrict__ Kb,
    __hip_bfloat16* __restrict__ Sb, float* __restrict__ lsum)
{
  const int z = blockIdx.z;
  const int m0 = blockIdx.y * 128, n0 = blockIdx.x * 128;
  if (n0 > m0) return;

  __shared__ __hip_bfloat16 As[128 * 32], Bs[128 * 32];
  const __hip_bfloat16* A = Qb + (size_t)z * SEQ * DMODEL;
  const __hip_bfloat16* B = Kb + (size_t)z * SEQ * DMODEL;
  __hip_bfloat16* outp = Sb + (size_t)z * SEQ * SEQ;
  floatx4 acc[4][4] = {};
  gemm_core(A, B, DMODEL, m0, n0, DMODEL / 32, As, Bs, acc);

  const int lane = threadIdx.x & 63, wave = threadIdx.x >> 6;
  const int quad = lane >> 4, r = lane & 15;
  const int wm = (wave >> 1) * 64, wn = (wave & 1) * 64;
  const float scale = 0.03125f;  // 1/sqrt(1024)
#pragma unroll
  for (int i = 0; i < 4; ++i) {
    const int mbase = m0 + wm + i * 16 + quad * 4;
#pragma unroll
    for (int e = 0; e < 4; ++e) {
      const int row = mbase + e;
      float p = 0.f;
#pragma unroll
      for (int j = 0; j < 4; ++j) {
        const int n = n0 + wn + j * 16 + r;
        const float pv = (n <= row) ? __expf(acc[i][j][e] * scale) : 0.f;
        outp[(size_t)row * SEQ + n] = __float2bfloat16(pv);
        p += pv;
      }
      // reduce over the 16 lanes of this quad (r = lane&15)
#pragma unroll
      for (int off = 1; off < 16; off <<= 1) p += __shfl_xor(p, off, 64);
      if (r == 0) atomicAdd(&lsum[z * SEQ + row], p);
    }
  }
}

// ---------------------------------------------------------------------------
// PV: Out[z][q][d] = (P'_z @ Vt_z^T)[q][d] / lsum[z*SEQ+q], fp32 out.
// K-loop truncated at the diagonal. grid = (8,16,4)
__global__ __launch_bounds__(256) void gemm_pv(
    const __hip_bfloat16* __restrict__ Sb, const __hip_bfloat16* __restrict__ Vt,
    const float* __restrict__ lsum, float* __restrict__ Out)
{
  __shared__ __hip_bfloat16 As[128 * 32], Bs[128 * 32];
  const int z = blockIdx.z;
  const int m0 = blockIdx.y * 128, n0 = blockIdx.x * 128;
  const __hip_bfloat16* A = Sb + (size_t)z * SEQ * SEQ;
  const __hip_bfloat16* B = Vt + (size_t)z * DMODEL * SEQ;
  float* outp = Out + (size_t)z * SEQ * DMODEL;

  floatx4 acc[4][4] = {};
  const int ktiles = (m0 + 128) / 32;  // causal truncation
  gemm_core(A, B, SEQ, m0, n0, ktiles, As, Bs, acc);

  const int lane = threadIdx.x & 63, wave = threadIdx.x >> 6;
  const int quad = lane >> 4, r = lane & 15;
  const int wm = (wave >> 1) * 64, wn = (wave & 1) * 64;
#pragma unroll
  for (int i = 0; i < 4; ++i) {
    const int mbase = m0 + wm + i * 16 + quad * 4;
    float inv[4];
#pragma unroll
    for (int e = 0; e < 4; ++e) inv[e] = 1.f / lsum[z * SEQ + mbase + e];
#pragma unroll
    for (int j = 0; j < 4; ++j) {
      const int n = n0 + wn + j * 16 + r;
#pragma unroll
      for (int e = 0; e < 4; ++e)
        outp[(size_t)(mbase + e) * DMODEL + n] = acc[i][j][e] * inv[e];
    }
  }
}

// ---------------------------------------------------------------------------
extern "C" void kernel_launch(void* const* d_in, const int* in_sizes, int n_in,
                              void* d_out, int out_size, void* d_ws, size_t ws_size,
                              hipStream_t stream)
{
  const float* X  = (const float*)d_in[0];
  const float* Wq = (const float*)d_in[1];
  const float* bq = (const float*)d_in[2];
  const float* Wk = (const float*)d_in[3];
  const float* bk = (const float*)d_in[4];
  const float* Wv = (const float*)d_in[5];
  const float* bv = (const float*)d_in[6];
  float* Out = (float*)d_out;

  // Workspace layout (~103 MB total)
  char* ws = (char*)d_ws;
  size_t off = 0;
  auto alloc = [&](size_t bytes) -> void* {
    void* p = ws + off;
    off += (bytes + 255) & ~(size_t)255;
    return p;
  };
  __hip_bfloat16* Xb  = (__hip_bfloat16*)alloc((size_t)MTOT * DMODEL * 2);    // 16 MB
  __hip_bfloat16* Wqb = (__hip_bfloat16*)alloc((size_t)DMODEL * DMODEL * 2);  // 2 MB
  __hip_bfloat16* Wkb = (__hip_bfloat16*)alloc((size_t)DMODEL * DMODEL * 2);
  __hip_bfloat16* Wvb = (__hip_bfloat16*)alloc((size_t)DMODEL * DMODEL * 2);
  __hip_bfloat16* Qb  = (__hip_bfloat16*)alloc((size_t)MTOT * DMODEL * 2);    // 16 MB
  __hip_bfloat16* Kb  = (__hip_bfloat16*)alloc((size_t)MTOT * DMODEL * 2);    // 16 MB
  __hip_bfloat16* Vt  = (__hip_bfloat16*)alloc((size_t)MTOT * DMODEL * 2);    // 16 MB
  __hip_bfloat16* Sb  = (__hip_bfloat16*)alloc((size_t)NBATCH * SEQ * SEQ * 2); // 32 MB
  float*          lsum = (float*)alloc((size_t)MTOT * 4);                     // 32 KB
  (void)ws_size; (void)in_sizes; (void)n_in; (void)out_size;

  // lsum must start at 0 (ws is re-poisoned to 0xAA before every launch)
  hipMemsetAsync(lsum, 0, (size_t)MTOT * 4, stream);
  // 1) converts (one kernel)
  convert_all<<<11264, 256, 0, stream>>>(X, Wq, Wk, Wv, Xb, Wqb, Wkb, Wvb);
  // 2) fused QKV projection (128x64 tiles); V written transposed
  gemm_qkv_fused<<<dim3(DMODEL / 64, MTOT / 128), 256, 0, stream>>>(
      Xb, Wqb, Wkb, Wvb, bq, bk, bv, Qb, Kb, Vt);
  // 3) scores: P' = exp(s), causal, + atomic row sums
  gemm_scores<<<dim3(SEQ / 128, SEQ / 128, NBATCH), 256, 0, stream>>>(Qb, Kb, Sb, lsum);
  // 4) PV with epilogue normalization -> output
  gemm_pv<<<dim3(DMODEL / 128, SEQ / 128, NBATCH), 256, 0, stream>>>(Sb, Vt, lsum, Out);
}

// Round 6
// 265.400 us; speedup vs baseline: 1.0370x; 1.0370x over previous
//
#include <hip/hip_runtime.h>
#include <hip/hip_bf16.h>

// Self-attention: q=X@Wq.T+bq, k=..., v=...; S = causal_softmax(q k^T / 32); O = S v
// B=4, S=2048, D_IN=D_OUT=1024. fp32 in/out; internal compute bf16 MFMA + fp32 acc.
//
// R6 changes:
//  - qkv reverted to R4's 128x128 3-way-fused tile (best measured: 65 us, 780 TF).
//    R5's 128x64 retile regressed (MFMA-per-barrier dominates blocks/CU).
//  - scores & pv widened to 128m x 256n tiles (A staged once/k-iter, 4x64-row
//    B chunks): 32 MFMA/wave/barrier (was 16), 6 stage16/iter, 24 KB LDS,
//    acc[4][8]=128 AGPR. Same lever that took qkv 686->780 TF in R3.
//
// MFMA fragment layouts (HW-verified per guide §3):
//  A: lane holds A[m=lane&15][k=(lane>>4)*8+j], j=0..7
//  B: lane holds B[k=(lane>>4)*8+j][n=lane&15]
//  C/D: lane holds D[row=(lane>>4)*4+e][col=lane&15], e=0..3

typedef __attribute__((ext_vector_type(8))) short short8;   // 8 bf16 = 4 VGPRs
typedef __attribute__((ext_vector_type(4))) float floatx4;  // MFMA acc

#define SEQ   2048
#define DMODEL 1024
#define NBATCH 4
#define MTOT  (SEQ * NBATCH)

// Direct global->LDS async copy, 16B per lane. LDS dst is wave-uniform base +
// lane*16 (per-lane scatter NOT supported) — our tile layout is lane-contiguous.
__device__ __forceinline__ void stage16(const __hip_bfloat16* g, __hip_bfloat16* l)
{
  __builtin_amdgcn_global_load_lds(
      (const __attribute__((address_space(1))) void*)g,
      (__attribute__((address_space(3))) void*)l, 16, 0, 0);
}

__device__ __forceinline__ unsigned short bf16_bits(float f)
{
  __hip_bfloat16 h = __float2bfloat16(f);
  return *(unsigned short*)&h;
}

// ---------------------------------------------------------------------------
// One-kernel fp32 -> bf16 convert for all four inputs. Each block: 1024 elems.
__global__ __launch_bounds__(256) void convert_all(
    const float* __restrict__ X,  const float* __restrict__ Wq,
    const float* __restrict__ Wk, const float* __restrict__ Wv,
    __hip_bfloat16* __restrict__ Xb,  __hip_bfloat16* __restrict__ Wqb,
    __hip_bfloat16* __restrict__ Wkb, __hip_bfloat16* __restrict__ Wvb)
{
  const int b = blockIdx.x;
  const float* src; __hip_bfloat16* dst; int rel;
  if (b < 8192)       { src = X;  dst = Xb;  rel = b; }
  else if (b < 9216)  { src = Wq; dst = Wqb; rel = b - 8192; }
  else if (b < 10240) { src = Wk; dst = Wkb; rel = b - 9216; }
  else                { src = Wv; dst = Wvb; rel = b - 10240; }
  const int i = rel * 1024 + threadIdx.x * 4;
  float4 f = *(const float4*)(src + i);
  uint2 o;
  o.x = (unsigned)bf16_bits(f.x) | ((unsigned)bf16_bits(f.y) << 16);
  o.y = (unsigned)bf16_bits(f.z) | ((unsigned)bf16_bits(f.w) << 16);
  *(uint2*)(dst + i) = o;
}

// ---------------------------------------------------------------------------
// Fused QKV projection (R4 version). A-tile (X) staged once per k-iter, three
// 128x32 B-tiles; 48 MFMA/wave/barrier. Q,K row-major; V transposed to Vt.
// grid = (DMODEL/128=8, MTOT/128=64), 256 threads, 32 KB LDS.
__global__ __launch_bounds__(256, 2) void gemm_qkv_fused(
    const __hip_bfloat16* __restrict__ Xb,
    const __hip_bfloat16* __restrict__ Wqb,
    const __hip_bfloat16* __restrict__ Wkb,
    const __hip_bfloat16* __restrict__ Wvb,
    const float* __restrict__ bq, const float* __restrict__ bk, const float* __restrict__ bv,
    __hip_bfloat16* __restrict__ Qb, __hip_bfloat16* __restrict__ Kb, __hip_bfloat16* __restrict__ Vt)
{
  __shared__ __hip_bfloat16 As[128 * 32];
  __shared__ __hip_bfloat16 Bs[3][128 * 32];
  const int m0 = blockIdx.y * 128, n0 = blockIdx.x * 128;
  const int tid  = threadIdx.x;
  const int lane = tid & 63;
  const int wave = tid >> 6;
  const int quad = lane >> 4;
  const int r    = lane & 15;
  const int wm   = (wave >> 1) * 64;
  const int wn   = (wave & 1) * 64;
  const int srow = wave * 16 + (lane >> 2);   // 0..63
  const int scol = (lane & 3) * 8;            // 0,8,16,24

  const __hip_bfloat16* Wp[3] = {Wqb, Wkb, Wvb};

  __hip_bfloat16* lA0 = As + wave * 512;
  __hip_bfloat16* lA1 = As + 2048 + wave * 512;

  const __hip_bfloat16* aR0 = Xb + (size_t)(m0 + srow) * DMODEL + scol;
  const __hip_bfloat16* aR1 = aR0 + (size_t)64 * DMODEL;

  floatx4 acc[3][4][4] = {};

  for (int kt = 0; kt < DMODEL / 32; ++kt) {
    const int k0 = kt * 32;
    stage16(aR0 + k0, lA0);
    stage16(aR1 + k0, lA1);
#pragma unroll
    for (int w = 0; w < 3; ++w) {
      stage16(Wp[w] + (size_t)(n0 + srow) * DMODEL + scol + k0,      Bs[w] + wave * 512);
      stage16(Wp[w] + (size_t)(n0 + 64 + srow) * DMODEL + scol + k0, Bs[w] + 2048 + wave * 512);
    }
    __syncthreads();
    short8 a[4];
#pragma unroll
    for (int i = 0; i < 4; ++i)
      a[i] = *(const short8*)(As + (wm + i * 16 + r) * 32 + quad * 8);
#pragma unroll
    for (int w = 0; w < 3; ++w) {
      short8 b[4];
#pragma unroll
      for (int j = 0; j < 4; ++j)
        b[j] = *(const short8*)(Bs[w] + (wn + j * 16 + r) * 32 + quad * 8);
#pragma unroll
      for (int i = 0; i < 4; ++i)
#pragma unroll
        for (int j = 0; j < 4; ++j)
          acc[w][i][j] = __builtin_amdgcn_mfma_f32_16x16x32_bf16(a[i], b[j], acc[w][i][j], 0, 0, 0);
    }
    __syncthreads();
  }

  // Q, K: row-major stores
  {
    __hip_bfloat16* Op[2] = {Qb, Kb};
    const float* Bp[2] = {bq, bk};
#pragma unroll
    for (int w = 0; w < 2; ++w) {
      __hip_bfloat16* out = Op[w];
#pragma unroll
      for (int j = 0; j < 4; ++j) {
        const int n = n0 + wn + j * 16 + r;
        const float bb = Bp[w][n];
#pragma unroll
        for (int i = 0; i < 4; ++i) {
          const int mbase = m0 + wm + i * 16 + quad * 4;
#pragma unroll
          for (int e = 0; e < 4; ++e)
            out[(size_t)(mbase + e) * DMODEL + n] = __float2bfloat16(acc[w][i][j][e] + bb);
        }
      }
    }
  }
  // V: transposed store Vt[z][d=n][pos], 8B packed per (i,j). z = batch of m0.
  {
    const int z    = m0 >> 11;           // SEQ = 2048
    const int posb = (m0 & (SEQ - 1)) + wm;
    __hip_bfloat16* vt = Vt + (size_t)z * DMODEL * SEQ;
#pragma unroll
    for (int j = 0; j < 4; ++j) {
      const int n = n0 + wn + j * 16 + r;
      const float bb = bv[n];
#pragma unroll
      for (int i = 0; i < 4; ++i) {
        const int pos = posb + i * 16 + quad * 4;
        unsigned long long pk =
            (unsigned long long)bf16_bits(acc[2][i][j][0] + bb)
          | ((unsigned long long)bf16_bits(acc[2][i][j][1] + bb) << 16)
          | ((unsigned long long)bf16_bits(acc[2][i][j][2] + bb) << 32)
          | ((unsigned long long)bf16_bits(acc[2][i][j][3] + bb) << 48);
        *(unsigned long long*)(vt + (size_t)n * SEQ + pos) = pk;
      }
    }
  }
}

// ---------------------------------------------------------------------------
// Wide GEMM core: C[128x256] += A * B^T, A/B bf16 row-major [.,K].
// A staged once per k-iter (2 chunks), B in 4x64-row chunks; 32 MFMA/wave/brr.
// Waves 2x2: wm in {0,64}, wn in {0,128}; each wave owns 64m x 128n.
__device__ __forceinline__ void gemm_core_256(
    const __hip_bfloat16* __restrict__ A,
    const __hip_bfloat16* __restrict__ B,
    int K, int m0, int n0, int ktiles,
    __hip_bfloat16* As /*128x32*/, __hip_bfloat16* Bs /*256x32*/,
    floatx4 acc[4][8])
{
  const int tid  = threadIdx.x;
  const int lane = tid & 63;
  const int wave = tid >> 6;
  const int quad = lane >> 4;
  const int r    = lane & 15;
  const int wm   = (wave >> 1) * 64;
  const int wn   = (wave & 1) * 128;
  const int srow = wave * 16 + (lane >> 2);   // 0..63
  const int scol = (lane & 3) * 8;

  for (int kt = 0; kt < ktiles; ++kt) {
    const int k0 = kt * 32;
    stage16(A + (size_t)(m0 + srow) * K + k0 + scol,      As + wave * 512);
    stage16(A + (size_t)(m0 + 64 + srow) * K + k0 + scol, As + 2048 + wave * 512);
#pragma unroll
    for (int c = 0; c < 4; ++c)
      stage16(B + (size_t)(n0 + c * 64 + srow) * K + k0 + scol, Bs + c * 2048 + wave * 512);
    __syncthreads();
    short8 a[4], b[8];
#pragma unroll
    for (int i = 0; i < 4; ++i)
      a[i] = *(const short8*)(As + (wm + i * 16 + r) * 32 + quad * 8);
#pragma unroll
    for (int j = 0; j < 8; ++j)
      b[j] = *(const short8*)(Bs + (wn + j * 16 + r) * 32 + quad * 8);
#pragma unroll
    for (int i = 0; i < 4; ++i)
#pragma unroll
      for (int j = 0; j < 8; ++j)
        acc[i][j] = __builtin_amdgcn_mfma_f32_16x16x32_bf16(a[i], b[j], acc[i][j], 0, 0, 0);
    __syncthreads();
  }
}

// ---------------------------------------------------------------------------
// Scores: P'[z][q][k] = exp((Qb_z Kb_z^T)[q][k]/32) for k<=q (0 above diagonal
// within diagonal tiles), bf16. Per-row partial sums atomically accumulated
// into lsum. Tiles fully above the diagonal: skipped (PV never reads them).
// 128m x 256n tiles; grid = (SEQ/256=8, SEQ/128=16, 4).
__global__ __launch_bounds__(256, 2) void gemm_scores(
    const __hip_bfloat16* __restrict__ Qb, const __hip_bfloat16* __restrict__ Kb,
    __hip_bfloat16* __restrict__ Sb, float* __restrict__ lsum)
{
  const int z = blockIdx.z;
  const int m0 = blockIdx.y * 128, n0 = blockIdx.x * 256;
  if (n0 >= m0 + 128) return;   // no element of this tile satisfies n <= m

  __shared__ __hip_bfloat16 As[128 * 32], Bs[256 * 32];
  const __hip_bfloat16* A = Qb + (size_t)z * SEQ * DMODEL;
  const __hip_bfloat16* B = Kb + (size_t)z * SEQ * DMODEL;
  __hip_bfloat16* outp = Sb + (size_t)z * SEQ * SEQ;
  floatx4 acc[4][8] = {};
  gemm_core_256(A, B, DMODEL, m0, n0, DMODEL / 32, As, Bs, acc);

  const int lane = threadIdx.x & 63, wave = threadIdx.x >> 6;
  const int quad = lane >> 4, r = lane & 15;
  const int wm = (wave >> 1) * 64, wn = (wave & 1) * 128;
  const float scale = 0.03125f;  // 1/sqrt(1024)
#pragma unroll
  for (int i = 0; i < 4; ++i) {
    const int mbase = m0 + wm + i * 16 + quad * 4;
#pragma unroll
    for (int e = 0; e < 4; ++e) {
      const int row = mbase + e;
      float p = 0.f;
#pragma unroll
      for (int j = 0; j < 8; ++j) {
        const int n = n0 + wn + j * 16 + r;
        const float pv = (n <= row) ? __expf(acc[i][j][e] * scale) : 0.f;
        outp[(size_t)row * SEQ + n] = __float2bfloat16(pv);
        p += pv;
      }
      // reduce over the 16 lanes of this quad (xor within r bits)
#pragma unroll
      for (int off = 1; off < 16; off <<= 1) p += __shfl_xor(p, off, 64);
      if (r == 0) atomicAdd(&lsum[z * SEQ + row], p);
    }
  }
}

// ---------------------------------------------------------------------------
// PV: Out[z][q][d] = (P'_z @ Vt_z^T)[q][d] / lsum[z*SEQ+q], fp32 out.
// 128m x 256n tiles; K-loop truncated at the diagonal. grid = (4,16,4).
__global__ __launch_bounds__(256, 2) void gemm_pv(
    const __hip_bfloat16* __restrict__ Sb, const __hip_bfloat16* __restrict__ Vt,
    const float* __restrict__ lsum, float* __restrict__ Out)
{
  __shared__ __hip_bfloat16 As[128 * 32], Bs[256 * 32];
  const int z = blockIdx.z;
  const int m0 = blockIdx.y * 128, n0 = blockIdx.x * 256;
  const __hip_bfloat16* A = Sb + (size_t)z * SEQ * SEQ;
  const __hip_bfloat16* B = Vt + (size_t)z * DMODEL * SEQ;
  float* outp = Out + (size_t)z * SEQ * DMODEL;

  floatx4 acc[4][8] = {};
  const int ktiles = (m0 + 128) / 32;  // causal truncation
  gemm_core_256(A, B, SEQ, m0, n0, ktiles, As, Bs, acc);

  const int lane = threadIdx.x & 63, wave = threadIdx.x >> 6;
  const int quad = lane >> 4, r = lane & 15;
  const int wm = (wave >> 1) * 64, wn = (wave & 1) * 128;
#pragma unroll
  for (int i = 0; i < 4; ++i) {
    const int mbase = m0 + wm + i * 16 + quad * 4;
    float inv[4];
#pragma unroll
    for (int e = 0; e < 4; ++e) inv[e] = 1.f / lsum[z * SEQ + mbase + e];
#pragma unroll
    for (int j = 0; j < 8; ++j) {
      const int n = n0 + wn + j * 16 + r;
#pragma unroll
      for (int e = 0; e < 4; ++e)
        outp[(size_t)(mbase + e) * DMODEL + n] = acc[i][j][e] * inv[e];
    }
  }
}

// ---------------------------------------------------------------------------
extern "C" void kernel_launch(void* const* d_in, const int* in_sizes, int n_in,
                              void* d_out, int out_size, void* d_ws, size_t ws_size,
                              hipStream_t stream)
{
  const float* X  = (const float*)d_in[0];
  const float* Wq = (const float*)d_in[1];
  const float* bq = (const float*)d_in[2];
  const float* Wk = (const float*)d_in[3];
  const float* bk = (const float*)d_in[4];
  const float* Wv = (const float*)d_in[5];
  const float* bv = (const float*)d_in[6];
  float* Out = (float*)d_out;

  // Workspace layout (~103 MB total)
  char* ws = (char*)d_ws;
  size_t off = 0;
  auto alloc = [&](size_t bytes) -> void* {
    void* p = ws + off;
    off += (bytes + 255) & ~(size_t)255;
    return p;
  };
  __hip_bfloat16* Xb  = (__hip_bfloat16*)alloc((size_t)MTOT * DMODEL * 2);    // 16 MB
  __hip_bfloat16* Wqb = (__hip_bfloat16*)alloc((size_t)DMODEL * DMODEL * 2);  // 2 MB
  __hip_bfloat16* Wkb = (__hip_bfloat16*)alloc((size_t)DMODEL * DMODEL * 2);
  __hip_bfloat16* Wvb = (__hip_bfloat16*)alloc((size_t)DMODEL * DMODEL * 2);
  __hip_bfloat16* Qb  = (__hip_bfloat16*)alloc((size_t)MTOT * DMODEL * 2);    // 16 MB
  __hip_bfloat16* Kb  = (__hip_bfloat16*)alloc((size_t)MTOT * DMODEL * 2);    // 16 MB
  __hip_bfloat16* Vt  = (__hip_bfloat16*)alloc((size_t)MTOT * DMODEL * 2);    // 16 MB
  __hip_bfloat16* Sb  = (__hip_bfloat16*)alloc((size_t)NBATCH * SEQ * SEQ * 2); // 32 MB
  float*          lsum = (float*)alloc((size_t)MTOT * 4);                     // 32 KB
  (void)ws_size; (void)in_sizes; (void)n_in; (void)out_size;

  // lsum must start at 0 (ws is re-poisoned to 0xAA before every launch)
  hipMemsetAsync(lsum, 0, (size_t)MTOT * 4, stream);
  // 1) converts (one kernel)
  convert_all<<<11264, 256, 0, stream>>>(X, Wq, Wk, Wv, Xb, Wqb, Wkb, Wvb);
  // 2) fused QKV projection (128x128, R4 version); V written transposed
  gemm_qkv_fused<<<dim3(DMODEL / 128, MTOT / 128), 256, 0, stream>>>(
      Xb, Wqb, Wkb, Wvb, bq, bk, bv, Qb, Kb, Vt);
  // 3) scores: P' = exp(s), causal, + atomic row sums (128x256 tiles)
  gemm_scores<<<dim3(SEQ / 256, SEQ / 128, NBATCH), 256, 0, stream>>>(Qb, Kb, Sb, lsum);
  // 4) PV with epilogue normalization (128x256 tiles) -> output
  gemm_pv<<<dim3(DMODEL / 256, SEQ / 128, NBATCH), 256, 0, stream>>>(Sb, Vt, lsum, Out);
}